// Round 15
// baseline (306.095 us; speedup 1.0000x reference)
//
#include <hip/hip_runtime.h>
#include <hip/hip_bf16.h>
#include <hip/hip_cooperative_groups.h>
#include <math.h>

namespace cg = cooperative_groups;

#define S_LEN 2048
#define HID   1024
#define INNER 2048
#define NCONV 4
#define LSTATE 16
#define DRANK 64
#define XPW   96   // DRANK + 2*LSTATE
#define CHUNK 32
#define NCHUNK (S_LEN / CHUNK)   // 64
#define XPAD  128  // padded N for the xp GEMM tile
#define XPSPLIT 16 // K-split for the xp GEMM
#define OSPLIT  2  // K-split for the out GEMM

typedef __attribute__((ext_vector_type(8))) short bf16x8;
typedef __attribute__((ext_vector_type(4))) float f32x4;

__device__ __forceinline__ short f2bf(float f) {
  union { __hip_bfloat16 h; short s; } u;
  u.h = __float2bfloat16(f);
  return u.s;
}

// fast exp: v_exp_f32-based (~1-2 ulp) — bf16 noise floor dominates anyway
__device__ __forceinline__ float fexp(float x) { return __expf(x); }

// async global->LDS, 16B per lane; lds dest = wave-uniform base + lane*16
#define GLDS(gp, lp) __builtin_amdgcn_global_load_lds(                         \
    (const __attribute__((address_space(1))) unsigned int*)(gp),               \
    (__attribute__((address_space(3))) unsigned int*)(lp), 16, 0, 0)

// ---------------- fused prep: cast x + transpose-cast 4 weights -------------
#define NB_CAST (S_LEN * HID / 4 / 256)            // 2048
#define NB_WIN  ((2 * INNER / 32) * (HID / 32))    // 4096
#define NB_WOUT ((HID / 32) * (INNER / 32))        // 2048
#define NB_WX   ((XPAD / 32) * (INNER / 32))       // 256
#define NB_WD   ((INNER / 32) * (DRANK / 32))      // 128
#define NB_PREP (NB_CAST + NB_WIN + NB_WOUT + NB_WX + NB_WD)
__global__ __launch_bounds__(256) void prep_kernel(
    const float* __restrict__ x, short* __restrict__ xb,
    const float* __restrict__ W_in, short* __restrict__ WinT,
    const float* __restrict__ W_out, short* __restrict__ WoutT,
    const float* __restrict__ W_x, short* __restrict__ WxT,
    const float* __restrict__ W_delta, short* __restrict__ WdT) {
  const int b = blockIdx.x;
  if (b < NB_CAST) {                       // cast x -> xb (bf16), float4/thread
    int i = b * 256 + threadIdx.x;
    const float4 v = ((const float4*)x)[i];
    short4 o;
    o.x = f2bf(v.x); o.y = f2bf(v.y); o.z = f2bf(v.z); o.w = f2bf(v.w);
    ((short4*)xb)[i] = o;
    return;
  }
  // transpose+cast in[R][C] -> out[Cpad][R], pad cols >= C zeroed
  __shared__ float tile[32][33];
  const float* in; short* outp; int R, C, bx, by;
  if (b < NB_CAST + NB_WIN) {
    int bb = b - NB_CAST;
    in = W_in; outp = WinT; R = HID; C = 2 * INNER;
    bx = bb % (2 * INNER / 32); by = bb / (2 * INNER / 32);
  } else if (b < NB_CAST + NB_WIN + NB_WOUT) {
    int bb = b - NB_CAST - NB_WIN;
    in = W_out; outp = WoutT; R = INNER; C = HID;
    bx = bb % (HID / 32); by = bb / (HID / 32);
  } else if (b < NB_CAST + NB_WIN + NB_WOUT + NB_WX) {
    int bb = b - NB_CAST - NB_WIN - NB_WOUT;
    in = W_x; outp = WxT; R = INNER; C = XPW;   // grid covers Cpad=XPAD
    bx = bb % (XPAD / 32); by = bb / (XPAD / 32);
  } else {
    int bb = b - NB_CAST - NB_WIN - NB_WOUT - NB_WX;
    in = W_delta; outp = WdT; R = DRANK; C = INNER;   // -> WdT[2048][64]
    bx = bb % (INNER / 32); by = bb / (INNER / 32);
  }
  const int bc = bx * 32, br = by * 32;
  const int tx = threadIdx.x & 31, ty = threadIdx.x >> 5;   // 32 x 8
  #pragma unroll
  for (int i = 0; i < 32; i += 8)
    tile[ty + i][tx] = (bc + tx < C)
        ? in[(size_t)(br + ty + i) * C + bc + tx] : 0.f;
  __syncthreads();
  #pragma unroll
  for (int i = 0; i < 32; i += 8)
    outp[(size_t)(bc + ty + i) * R + br + tx] = f2bf(tile[tx][ty + i]);
}

// --------------- bf16 MFMA GEMM: C[M,N] = A[M,K] @ Bt[N,K]^T ---------------
// 128x128 tile, BK=32, 8 waves (2M x 4N). 4-buffer pipeline, depth-3 counted
// vmcnt (T4). LDS 16B-slot XOR swizzle (involution, rule #21) -> 0 conflicts.
// EPI: 0 = plain store, 1 = softplus(acc + bias[col]) store.
#define BK   32
#define NBUF 4
template<int EPI>
__global__ __launch_bounds__(512) void gemm_bf16(
    const short* __restrict__ A,  int lda,    // [M,K] bf16 row-major
    const short* __restrict__ Bt, int ldb,    // [N,K] bf16 row-major
    float* __restrict__ C, int ldc,
    int kPerSplit, size_t cSliceStride,
    const float* __restrict__ bias) {
  __shared__ short As[NBUF][128 * BK];
  __shared__ short Bs[NBUF][128 * BK];
  const int tid  = threadIdx.x;
  const int lane = tid & 63;
  const int wave = tid >> 6;                  // 0..7
  const int bm = blockIdx.y * 128;
  const int bn = blockIdx.x * 128;
  const int wm = (wave & 1) * 64;             // 2 M-waves
  const int wn = (wave >> 1) * 32;            // 4 N-waves
  const int fr = lane & 15;
  const int fq = lane >> 4;
  const int kbeg = blockIdx.z * kPerSplit;
  const int nIter = kPerSplit / BK;
  float* Cw = C + (size_t)blockIdx.z * cSliceStride;

  // staging geometry: waves 0-3 stage A rows [sw*32,+32), waves 4-7 stage B
  const int sw  = wave & 3;
  const int rs0 = sw * 32 + (lane >> 2);
  const int rs1 = rs0 + 16;
  const int sg0 = (lane & 3) ^ ((rs0 >> 1) & 3);  // source 16B chunk (swz)
  const int sg1 = (lane & 3) ^ ((rs1 >> 1) & 3);
  const bool isB = wave >= 4;
  const short* gbase = isB ? Bt : A;
  const int    gld   = isB ? ldb : lda;
  const int    gro   = isB ? bn  : bm;
  const short* g0 = gbase + (size_t)(gro + rs0) * gld + kbeg + sg0 * 8;
  const short* g1 = gbase + (size_t)(gro + rs1) * gld + kbeg + sg1 * 8;
  const int lo0 = (sw * 32) * BK;             // shorts
  const int lo1 = (sw * 32 + 16) * BK;

  f32x4 acc[4][2] = {};

#define STAGE(tile, buf) do {                                                  \
    short* dst_ = isB ? &Bs[buf][0] : &As[buf][0];                             \
    const int ko_ = (tile) * BK;                                               \
    GLDS(g0 + ko_, dst_ + lo0);                                                \
    GLDS(g1 + ko_, dst_ + lo1);                                                \
  } while (0)

  STAGE(0, 0);
  if (nIter > 1) STAGE(1, 1);
  if (nIter > 2) STAGE(2, 2);

  const int sl = (fq ^ ((fr >> 1) & 3)) * 8;  // read-side swizzled slot
  for (int t = 0; t < nIter; ++t) {
    const int rem = nIter - 1 - t;
    if (rem >= 2)      asm volatile("s_waitcnt vmcnt(4)" ::: "memory");
    else if (rem == 1) asm volatile("s_waitcnt vmcnt(2)" ::: "memory");
    else               asm volatile("s_waitcnt vmcnt(0)" ::: "memory");
    asm volatile("s_barrier" ::: "memory");
    if (t + 3 < nIter) STAGE(t + 3, (t + 3) & 3);
    const int r = t & 3;
    bf16x8 af[4], bfv[2];
    #pragma unroll
    for (int mi = 0; mi < 4; ++mi)
      af[mi] = *(const bf16x8*)(&As[r][(wm + mi * 16 + fr) * BK + sl]);
    #pragma unroll
    for (int ni = 0; ni < 2; ++ni)
      bfv[ni] = *(const bf16x8*)(&Bs[r][(wn + ni * 16 + fr) * BK + sl]);
    #pragma unroll
    for (int mi = 0; mi < 4; ++mi)
      #pragma unroll
      for (int ni = 0; ni < 2; ++ni)
        acc[mi][ni] = __builtin_amdgcn_mfma_f32_16x16x32_bf16(
            af[mi], bfv[ni], acc[mi][ni], 0, 0, 0);
  }
#undef STAGE
  // C/D layout (m89): col = lane&15, row = (lane>>4)*4 + reg
  #pragma unroll
  for (int mi = 0; mi < 4; ++mi) {
    #pragma unroll
    for (int ni = 0; ni < 2; ++ni) {
      const int col = bn + wn + ni * 16 + fr;
      #pragma unroll
      for (int r = 0; r < 4; ++r) {
        const int row = bm + wm + mi * 16 + fq * 4 + r;
        float v = acc[mi][ni][r];
        if (EPI == 1) {
          v += bias[col];
          v = fmaxf(v, 0.f) + log1pf(expf(-fabsf(v)));   // softplus (precise)
        }
        Cw[(size_t)row * ldc + col] = v;
      }
    }
  }
}

// ---- reduce XPSPLIT partials [Z][S][XPAD] -> xp [S][XPW] + xpb64 bf16 ------
__global__ __launch_bounds__(256) void reduce_xp_kernel(
    const float* __restrict__ part, float* __restrict__ xp,
    short* __restrict__ xpb64) {
  int i4 = blockIdx.x * 256 + threadIdx.x;
  if (i4 >= S_LEN * (XPW / 4)) return;
  int m = i4 / (XPW / 4);
  int n4 = i4 - m * (XPW / 4);
  const float4* p = (const float4*)part;
  const size_t rowv = (size_t)m * (XPAD / 4) + n4;
  const size_t slice = (size_t)S_LEN * (XPAD / 4);
  float4 o = p[rowv];
  #pragma unroll
  for (int s = 1; s < XPSPLIT; ++s) {   // fixed order: deterministic
    float4 v = p[rowv + s * slice];
    o.x += v.x; o.y += v.y; o.z += v.z; o.w += v.w;
  }
  ((float4*)xp)[i4] = o;
  if (n4 < DRANK / 4) {                 // bf16 copy of delta-GEMM A-operand
    short4 s4;
    s4.x = f2bf(o.x); s4.y = f2bf(o.y); s4.z = f2bf(o.z); s4.w = f2bf(o.w);
    ((short4*)xpb64)[m * (DRANK / 4) + n4] = s4;
  }
}

// ------------- reduce OSPLIT partials [Z][S][HID] -> out --------------------
__global__ __launch_bounds__(256) void reduce_out_kernel(
    const float* __restrict__ part, float* __restrict__ out) {
  int i4 = blockIdx.x * 256 + threadIdx.x;
  if (i4 >= S_LEN * (HID / 4)) return;
  const float4* p = (const float4*)part;
  const size_t slice = (size_t)S_LEN * (HID / 4);
  float4 o = p[i4];
  #pragma unroll
  for (int s = 1; s < OSPLIT; ++s) {
    float4 v = p[i4 + s * slice];
    o.x += v.x; o.y += v.y; o.z += v.z; o.w += v.w;
  }
  ((float4*)out)[i4] = o;
}

// ------- depthwise causal conv (width 4) + bias + SiLU, float4/thread -------
__global__ __launch_bounds__(256) void conv_silu_kernel(
    const float* __restrict__ xz,
    const float* __restrict__ cw,
    const float* __restrict__ cb,
    float* __restrict__ xc,
    short* __restrict__ xcb) {
  int i4 = blockIdx.x * 256 + threadIdx.x;       // over S*INNER/4
  if (i4 >= S_LEN * INNER / 4) return;
  int s = i4 / (INNER / 4);
  int cg = i4 - s * (INNER / 4);                 // 4-channel group
  float4 acc = ((const float4*)cb)[cg];
  #pragma unroll
  for (int k = 0; k < NCONV; ++k) {
    int t = s - (NCONV - 1) + k;
    if (t >= 0) {
      float4 xv = *(const float4*)(xz + (size_t)t * (2 * INNER) + cg * 4);
      float4 wv = ((const float4*)(cw + k * INNER))[cg];
      acc.x += xv.x * wv.x; acc.y += xv.y * wv.y;
      acc.z += xv.z * wv.z; acc.w += xv.w * wv.w;
    }
  }
  float4 v;
  v.x = acc.x / (1.f + fexp(-acc.x));
  v.y = acc.y / (1.f + fexp(-acc.y));
  v.z = acc.z / (1.f + fexp(-acc.z));
  v.w = acc.w / (1.f + fexp(-acc.w));
  ((float4*)xc)[i4] = v;
  short4 o;
  o.x = f2bf(v.x); o.y = f2bf(v.y); o.z = f2bf(v.z); o.w = f2bf(v.w);
  ((short4*)xcb)[i4] = o;
}

// -------------- fused chunk-parallel SSM scan (cooperative) -----------------
// phase1: local scan per (chunk, d) -> Aprod/Hend.  grid.sync()
// phase2: 128 flat blocks compose carries -> Hin.   grid.sync()
// phase3: replay from Hin with fused epilogue -> ybf (bf16).
// a[16] registers and Bc/Cc LDS tiles are loaded once and reused in phase3.
__global__ __launch_bounds__(256) void scan_fused(
    const float* __restrict__ delta,
    const float* __restrict__ xp,
    const float* __restrict__ xc,
    const float* __restrict__ xz,
    const float* __restrict__ A_log,
    const float* __restrict__ Dvec,
    float* __restrict__ Aprod,
    float* __restrict__ Hend,
    float* __restrict__ Hin,
    short* __restrict__ ybf) {
  __shared__ float Bc[CHUNK][LSTATE];
  __shared__ float Cc[CHUNK][LSTATE];
  const int tid = threadIdx.x;
  const int d = blockIdx.y * 256 + tid;
  const int c = blockIdx.x;
  const int s0 = c * CHUNK;
  for (int u = tid; u < CHUNK * LSTATE; u += 256) {
    int r = u >> 4, l = u & 15;
    size_t base = (size_t)(s0 + r) * XPW + DRANK;
    Bc[r][l] = xp[base + l];
    Cc[r][l] = xp[base + LSTATE + l];
  }
  float a[LSTATE];
  {
    const float4* Ar = (const float4*)(A_log + (size_t)d * LSTATE);
    #pragma unroll
    for (int q = 0; q < 4; ++q) {
      float4 v = Ar[q];
      a[q * 4 + 0] = -fexp(v.x);
      a[q * 4 + 1] = -fexp(v.y);
      a[q * 4 + 2] = -fexp(v.z);
      a[q * 4 + 3] = -fexp(v.w);
    }
  }
  __syncthreads();
  // ---- phase 1: local scan (h0 = 0), record Aprod & Hend ----
  {
    float h[LSTATE] = {}, ap[LSTATE];
    #pragma unroll
    for (int l = 0; l < LSTATE; ++l) ap[l] = 1.f;
    const float* pd = delta + (size_t)s0 * INNER + d;
    const float* px = xc    + (size_t)s0 * INNER + d;
    for (int i = 0; i < CHUNK; ++i) {
      float dv = *pd, xcv = *px;
      pd += INNER; px += INNER;
      float sc = dv * xcv;
      #pragma unroll
      for (int l = 0; l < LSTATE; ++l) {
        float dA = fexp(dv * a[l]);
        h[l] = fmaf(dA, h[l], sc * Bc[i][l]);
        ap[l] *= dA;
      }
    }
    float4* Ap = (float4*)(Aprod + ((size_t)c * INNER + d) * LSTATE);
    float4* Hp = (float4*)(Hend  + ((size_t)c * INNER + d) * LSTATE);
    #pragma unroll
    for (int q = 0; q < 4; ++q) {
      Ap[q] = make_float4(ap[q * 4], ap[q * 4 + 1], ap[q * 4 + 2], ap[q * 4 + 3]);
      Hp[q] = make_float4(h[q * 4], h[q * 4 + 1], h[q * 4 + 2], h[q * 4 + 3]);
    }
  }
  cg::this_grid().sync();
  // ---- phase 2: compose carries (128 flat blocks cover INNER*LSTATE) ----
  {
    const int flat = blockIdx.y * NCHUNK + blockIdx.x;
    if (flat < (INNER * LSTATE) / 256) {
      const int idx = flat * 256 + tid;
      const size_t stride = (size_t)INNER * LSTATE;
      float h = 0.f;
      for (int cb = 0; cb < NCHUNK; cb += 16) {
        float ap[16], he[16];
        #pragma unroll
        for (int j = 0; j < 16; ++j) {
          size_t o = (size_t)(cb + j) * stride + idx;
          ap[j] = Aprod[o];
          he[j] = Hend[o];
        }
        #pragma unroll
        for (int j = 0; j < 16; ++j) {
          size_t o = (size_t)(cb + j) * stride + idx;
          Hin[o] = h;
          h = ap[j] * h + he[j];
        }
      }
    }
  }
  cg::this_grid().sync();
  // ---- phase 3: replay from carry-in, fused +xc*D, *silu(z), bf16 cast ----
  {
    float h[LSTATE];
    const float4* Hi = (const float4*)(Hin + ((size_t)c * INNER + d) * LSTATE);
    #pragma unroll
    for (int q = 0; q < 4; ++q) {
      float4 v = Hi[q];
      h[q * 4 + 0] = v.x; h[q * 4 + 1] = v.y;
      h[q * 4 + 2] = v.z; h[q * 4 + 3] = v.w;
    }
    const float Dd = Dvec[d];
    const float* pd = delta + (size_t)s0 * INNER + d;
    const float* px = xc    + (size_t)s0 * INNER + d;
    const float* pz = xz + (size_t)s0 * (2 * INNER) + INNER + d;
    short* py = ybf + (size_t)s0 * INNER + d;
    for (int i = 0; i < CHUNK; ++i) {
      float dv = *pd, xcv = *px, zv = *pz;
      pd += INNER; px += INNER; pz += 2 * INNER;
      float sc = dv * xcv;
      float contrib = 0.f;
      #pragma unroll
      for (int l = 0; l < LSTATE; ++l) {
        float dA = fexp(dv * a[l]);
        h[l] = fmaf(dA, h[l], sc * Bc[i][l]);
        contrib = fmaf(h[l], Cc[i][l], contrib);
      }
      float silu_z = zv / (1.f + fexp(-zv));
      *py = f2bf(fmaf(xcv, Dd, contrib) * silu_z);
      py += INNER;
    }
  }
}

extern "C" void kernel_launch(void* const* d_in, const int* in_sizes, int n_in,
                              void* d_out, int out_size, void* d_ws, size_t ws_size,
                              hipStream_t stream) {
  const float* x      = (const float*)d_in[0];   // [S, HID]
  const float* W_in   = (const float*)d_in[1];   // [HID, 2*INNER]
  const float* conv_w = (const float*)d_in[2];   // [4,1,INNER]
  const float* conv_b = (const float*)d_in[3];   // [INNER]
  const float* W_x    = (const float*)d_in[4];   // [INNER, 96]
  const float* W_delta= (const float*)d_in[5];   // [DRANK, INNER]
  const float* b_delta= (const float*)d_in[6];   // [INNER]
  const float* A_log  = (const float*)d_in[7];   // [INNER, L]
  const float* Dvec   = (const float*)d_in[8];   // [INNER]
  const float* W_out  = (const float*)d_in[9];   // [INNER, HID]
  float* out = (float*)d_out;

  float* ws    = (float*)d_ws;
  float* xz    = ws;                               // S * 2*INNER
  float* xc    = xz + (size_t)S_LEN * 2 * INNER;   // S * INNER
  float* xp    = xc + (size_t)S_LEN * INNER;       // S * XPW
  float* delta = xp + (size_t)S_LEN * XPW;         // S * INNER
  float* Aprod = delta + (size_t)S_LEN * INNER;    // NCHUNK * INNER * L
  float* Hend  = Aprod + (size_t)NCHUNK * INNER * LSTATE;
  float* Hin   = Hend  + (size_t)NCHUNK * INNER * LSTATE;
  short* xb    = (short*)(Hin + (size_t)NCHUNK * INNER * LSTATE); // S*HID bf16
  short* WinT  = xb + (size_t)S_LEN * HID;          // [2*INNER, HID] bf16
  short* WoutT = WinT + (size_t)(2 * INNER) * HID;  // [HID, INNER] bf16
  short* ybf   = WoutT + (size_t)HID * INNER;       // [S, INNER] bf16
  short* xcb   = ybf + (size_t)S_LEN * INNER;       // [S, INNER] bf16
  short* WxT   = xcb + (size_t)S_LEN * INNER;       // [XPAD, INNER] bf16
  short* WdT   = WxT + (size_t)XPAD * INNER;        // [INNER, DRANK] bf16
  short* xpb64 = WdT + (size_t)INNER * DRANK;       // [S, DRANK] bf16
  // xp K-split partials [16][S][XPAD] = 16.8 MB alias Aprod..Hin (25.2 MB,
  // dead until the scan). out partials [2][S][HID] = 16.8 MB alias xc..delta
  // (dead after the scan).
  float* xpPart  = Aprod;
  float* outPart = xc;

  // 0. fused prep: cast x, transpose+cast W_in/W_out/W_x/W_delta
  prep_kernel<<<NB_PREP, 256, 0, stream>>>(
      x, xb, W_in, WinT, W_out, WoutT, W_x, WxT, W_delta, WdT);

  // 1. xz = x @ W_in   (M=2048, N=4096, K=1024)  [bf16 MFMA, 8-wave]
  gemm_bf16<0><<<dim3(4096 / 128, 2048 / 128, 1), 512, 0, stream>>>(
      xb, HID, WinT, HID, xz, 2 * INNER, HID, 0, nullptr);

  // 2. xc = silu(causal_depthwise_conv(xi) + conv_b)  (+ bf16 copy)
  conv_silu_kernel<<<(S_LEN * INNER / 4 + 255) / 256, 256, 0, stream>>>(
      xz, conv_w, conv_b, xc, xcb);

  // 3. xp = xc @ W_x   (M=2048, N=96, K=2048)  [bf16 MFMA, 16-way K-split]
  gemm_bf16<0><<<dim3(1, 2048 / 128, XPSPLIT), 512, 0, stream>>>(
      xcb, INNER, WxT, INNER, xpPart, XPAD, INNER / XPSPLIT,
      (size_t)S_LEN * XPAD, nullptr);
  reduce_xp_kernel<<<(S_LEN * (XPW / 4) + 255) / 256, 256, 0, stream>>>(
      xpPart, xp, xpb64);

  // 4. delta = softplus(xp[:, :64] @ W_delta + b_delta)  [bf16 MFMA + epi]
  gemm_bf16<1><<<dim3(2048 / 128, 2048 / 128, 1), 512, 0, stream>>>(
      xpb64, DRANK, WdT, DRANK, delta, INNER, DRANK, 0, b_delta);

  // 5. fused cooperative SSM scan -> ybf
  {
    void* args[] = {(void*)&delta, (void*)&xp, (void*)&xc, (void*)&xz,
                    (void*)&A_log, (void*)&Dvec, (void*)&Aprod, (void*)&Hend,
                    (void*)&Hin, (void*)&ybf};
    hipLaunchCooperativeKernel((const void*)scan_fused,
                               dim3(NCHUNK, INNER / 256), dim3(256),
                               args, 0, stream);
  }

  // 6. out = y @ W_out  (M=2048, N=1024, K=2048)  [bf16 MFMA, 2-way K-split]
  gemm_bf16<0><<<dim3(1024 / 128, 2048 / 128, OSPLIT), 512, 0, stream>>>(
      ybf, INNER, WoutT, INNER, outPart, HID, INNER / OSPLIT,
      (size_t)S_LEN * HID, nullptr);
  reduce_out_kernel<<<(S_LEN * (HID / 4) + 255) / 256, 256, 0, stream>>>(
      outPart, out);
}

// Round 16
// 165.194 us; speedup vs baseline: 1.8529x; 1.8529x over previous
//
#include <hip/hip_runtime.h>
#include <hip/hip_bf16.h>
#include <math.h>

#define S_LEN 2048
#define HID   1024
#define INNER 2048
#define NCONV 4
#define LSTATE 16
#define DRANK 64
#define XPW   96   // DRANK + 2*LSTATE
#define CHUNK 32
#define NCHUNK (S_LEN / CHUNK)   // 64
#define XPAD  128  // padded N for the xp GEMM tile
#define XPSPLIT 16 // K-split for the xp GEMM
#define OSPLIT  2  // K-split for the out GEMM

typedef __attribute__((ext_vector_type(8))) short bf16x8;
typedef __attribute__((ext_vector_type(4))) float f32x4;

__device__ __forceinline__ short f2bf(float f) {
  union { __hip_bfloat16 h; short s; } u;
  u.h = __float2bfloat16(f);
  return u.s;
}

// fast exp: v_exp_f32-based (~1-2 ulp) — bf16 noise floor dominates anyway
__device__ __forceinline__ float fexp(float x) { return __expf(x); }

// async global->LDS, 16B per lane; lds dest = wave-uniform base + lane*16
#define GLDS(gp, lp) __builtin_amdgcn_global_load_lds(                         \
    (const __attribute__((address_space(1))) unsigned int*)(gp),               \
    (__attribute__((address_space(3))) unsigned int*)(lp), 16, 0, 0)

// ---------------- fused prep: cast x + transpose-cast 4 weights -------------
#define NB_CAST (S_LEN * HID / 4 / 256)            // 2048
#define NB_WIN  ((2 * INNER / 32) * (HID / 32))    // 4096
#define NB_WOUT ((HID / 32) * (INNER / 32))        // 2048
#define NB_WX   ((XPAD / 32) * (INNER / 32))       // 256
#define NB_WD   ((INNER / 32) * (DRANK / 32))      // 128
#define NB_PREP (NB_CAST + NB_WIN + NB_WOUT + NB_WX + NB_WD)
__global__ __launch_bounds__(256) void prep_kernel(
    const float* __restrict__ x, short* __restrict__ xb,
    const float* __restrict__ W_in, short* __restrict__ WinT,
    const float* __restrict__ W_out, short* __restrict__ WoutT,
    const float* __restrict__ W_x, short* __restrict__ WxT,
    const float* __restrict__ W_delta, short* __restrict__ WdT) {
  const int b = blockIdx.x;
  if (b < NB_CAST) {                       // cast x -> xb (bf16), float4/thread
    int i = b * 256 + threadIdx.x;
    const float4 v = ((const float4*)x)[i];
    short4 o;
    o.x = f2bf(v.x); o.y = f2bf(v.y); o.z = f2bf(v.z); o.w = f2bf(v.w);
    ((short4*)xb)[i] = o;
    return;
  }
  // transpose+cast in[R][C] -> out[Cpad][R], pad cols >= C zeroed
  __shared__ float tile[32][33];
  const float* in; short* outp; int R, C, bx, by;
  if (b < NB_CAST + NB_WIN) {
    int bb = b - NB_CAST;
    in = W_in; outp = WinT; R = HID; C = 2 * INNER;
    bx = bb % (2 * INNER / 32); by = bb / (2 * INNER / 32);
  } else if (b < NB_CAST + NB_WIN + NB_WOUT) {
    int bb = b - NB_CAST - NB_WIN;
    in = W_out; outp = WoutT; R = INNER; C = HID;
    bx = bb % (HID / 32); by = bb / (HID / 32);
  } else if (b < NB_CAST + NB_WIN + NB_WOUT + NB_WX) {
    int bb = b - NB_CAST - NB_WIN - NB_WOUT;
    in = W_x; outp = WxT; R = INNER; C = XPW;   // grid covers Cpad=XPAD
    bx = bb % (XPAD / 32); by = bb / (XPAD / 32);
  } else {
    int bb = b - NB_CAST - NB_WIN - NB_WOUT - NB_WX;
    in = W_delta; outp = WdT; R = DRANK; C = INNER;   // -> WdT[2048][64]
    bx = bb % (INNER / 32); by = bb / (INNER / 32);
  }
  const int bc = bx * 32, br = by * 32;
  const int tx = threadIdx.x & 31, ty = threadIdx.x >> 5;   // 32 x 8
  #pragma unroll
  for (int i = 0; i < 32; i += 8)
    tile[ty + i][tx] = (bc + tx < C)
        ? in[(size_t)(br + ty + i) * C + bc + tx] : 0.f;
  __syncthreads();
  #pragma unroll
  for (int i = 0; i < 32; i += 8)
    outp[(size_t)(bc + ty + i) * R + br + tx] = f2bf(tile[tx][ty + i]);
}

// --------------- bf16 MFMA GEMM: C[M,N] = A[M,K] @ Bt[N,K]^T ---------------
// 128x128 tile, BK=32, 8 waves (2M x 4N). 4-buffer pipeline, depth-3 counted
// vmcnt (T4). LDS 16B-slot XOR swizzle (involution, rule #21) -> 0 conflicts.
// EPI: 0 = plain store, 1 = softplus(acc + bias[col]) store.
#define BK   32
#define NBUF 4
template<int EPI>
__global__ __launch_bounds__(512) void gemm_bf16(
    const short* __restrict__ A,  int lda,    // [M,K] bf16 row-major
    const short* __restrict__ Bt, int ldb,    // [N,K] bf16 row-major
    float* __restrict__ C, int ldc,
    int kPerSplit, size_t cSliceStride,
    const float* __restrict__ bias) {
  __shared__ short As[NBUF][128 * BK];
  __shared__ short Bs[NBUF][128 * BK];
  const int tid  = threadIdx.x;
  const int lane = tid & 63;
  const int wave = tid >> 6;                  // 0..7
  const int bm = blockIdx.y * 128;
  const int bn = blockIdx.x * 128;
  const int wm = (wave & 1) * 64;             // 2 M-waves
  const int wn = (wave >> 1) * 32;            // 4 N-waves
  const int fr = lane & 15;
  const int fq = lane >> 4;
  const int kbeg = blockIdx.z * kPerSplit;
  const int nIter = kPerSplit / BK;
  float* Cw = C + (size_t)blockIdx.z * cSliceStride;

  // staging geometry: waves 0-3 stage A rows [sw*32,+32), waves 4-7 stage B
  const int sw  = wave & 3;
  const int rs0 = sw * 32 + (lane >> 2);
  const int rs1 = rs0 + 16;
  const int sg0 = (lane & 3) ^ ((rs0 >> 1) & 3);  // source 16B chunk (swz)
  const int sg1 = (lane & 3) ^ ((rs1 >> 1) & 3);
  const bool isB = wave >= 4;
  const short* gbase = isB ? Bt : A;
  const int    gld   = isB ? ldb : lda;
  const int    gro   = isB ? bn  : bm;
  const short* g0 = gbase + (size_t)(gro + rs0) * gld + kbeg + sg0 * 8;
  const short* g1 = gbase + (size_t)(gro + rs1) * gld + kbeg + sg1 * 8;
  const int lo0 = (sw * 32) * BK;             // shorts
  const int lo1 = (sw * 32 + 16) * BK;

  f32x4 acc[4][2] = {};

#define STAGE(tile, buf) do {                                                  \
    short* dst_ = isB ? &Bs[buf][0] : &As[buf][0];                             \
    const int ko_ = (tile) * BK;                                               \
    GLDS(g0 + ko_, dst_ + lo0);                                                \
    GLDS(g1 + ko_, dst_ + lo1);                                                \
  } while (0)

  STAGE(0, 0);
  if (nIter > 1) STAGE(1, 1);
  if (nIter > 2) STAGE(2, 2);

  const int sl = (fq ^ ((fr >> 1) & 3)) * 8;  // read-side swizzled slot
  for (int t = 0; t < nIter; ++t) {
    const int rem = nIter - 1 - t;
    if (rem >= 2)      asm volatile("s_waitcnt vmcnt(4)" ::: "memory");
    else if (rem == 1) asm volatile("s_waitcnt vmcnt(2)" ::: "memory");
    else               asm volatile("s_waitcnt vmcnt(0)" ::: "memory");
    asm volatile("s_barrier" ::: "memory");
    if (t + 3 < nIter) STAGE(t + 3, (t + 3) & 3);
    const int r = t & 3;
    bf16x8 af[4], bfv[2];
    #pragma unroll
    for (int mi = 0; mi < 4; ++mi)
      af[mi] = *(const bf16x8*)(&As[r][(wm + mi * 16 + fr) * BK + sl]);
    #pragma unroll
    for (int ni = 0; ni < 2; ++ni)
      bfv[ni] = *(const bf16x8*)(&Bs[r][(wn + ni * 16 + fr) * BK + sl]);
    #pragma unroll
    for (int mi = 0; mi < 4; ++mi)
      #pragma unroll
      for (int ni = 0; ni < 2; ++ni)
        acc[mi][ni] = __builtin_amdgcn_mfma_f32_16x16x32_bf16(
            af[mi], bfv[ni], acc[mi][ni], 0, 0, 0);
  }
#undef STAGE
  // C/D layout (m89): col = lane&15, row = (lane>>4)*4 + reg
  #pragma unroll
  for (int mi = 0; mi < 4; ++mi) {
    #pragma unroll
    for (int ni = 0; ni < 2; ++ni) {
      const int col = bn + wn + ni * 16 + fr;
      #pragma unroll
      for (int r = 0; r < 4; ++r) {
        const int row = bm + wm + mi * 16 + fq * 4 + r;
        float v = acc[mi][ni][r];
        if (EPI == 1) {
          v += bias[col];
          v = fmaxf(v, 0.f) + log1pf(expf(-fabsf(v)));   // softplus (precise)
        }
        Cw[(size_t)row * ldc + col] = v;
      }
    }
  }
}

// ---- reduce XPSPLIT partials [Z][S][XPAD] -> xp [S][XPW] + xpb64 bf16 ------
__global__ __launch_bounds__(256) void reduce_xp_kernel(
    const float* __restrict__ part, float* __restrict__ xp,
    short* __restrict__ xpb64) {
  int i4 = blockIdx.x * 256 + threadIdx.x;
  if (i4 >= S_LEN * (XPW / 4)) return;
  int m = i4 / (XPW / 4);
  int n4 = i4 - m * (XPW / 4);
  const float4* p = (const float4*)part;
  const size_t rowv = (size_t)m * (XPAD / 4) + n4;
  const size_t slice = (size_t)S_LEN * (XPAD / 4);
  float4 o = p[rowv];
  #pragma unroll
  for (int s = 1; s < XPSPLIT; ++s) {   // fixed order: deterministic
    float4 v = p[rowv + s * slice];
    o.x += v.x; o.y += v.y; o.z += v.z; o.w += v.w;
  }
  ((float4*)xp)[i4] = o;
  if (n4 < DRANK / 4) {                 // bf16 copy of delta-GEMM A-operand
    short4 s4;
    s4.x = f2bf(o.x); s4.y = f2bf(o.y); s4.z = f2bf(o.z); s4.w = f2bf(o.w);
    ((short4*)xpb64)[m * (DRANK / 4) + n4] = s4;
  }
}

// ------------- reduce OSPLIT partials [Z][S][HID] -> out --------------------
__global__ __launch_bounds__(256) void reduce_out_kernel(
    const float* __restrict__ part, float* __restrict__ out) {
  int i4 = blockIdx.x * 256 + threadIdx.x;
  if (i4 >= S_LEN * (HID / 4)) return;
  const float4* p = (const float4*)part;
  const size_t slice = (size_t)S_LEN * (HID / 4);
  float4 o = p[i4];
  #pragma unroll
  for (int s = 1; s < OSPLIT; ++s) {
    float4 v = p[i4 + s * slice];
    o.x += v.x; o.y += v.y; o.z += v.z; o.w += v.w;
  }
  ((float4*)out)[i4] = o;
}

// ------- depthwise causal conv (width 4) + bias + SiLU, float4/thread -------
__global__ __launch_bounds__(256) void conv_silu_kernel(
    const float* __restrict__ xz,
    const float* __restrict__ cw,
    const float* __restrict__ cb,
    float* __restrict__ xc,
    short* __restrict__ xcb) {
  int i4 = blockIdx.x * 256 + threadIdx.x;       // over S*INNER/4
  if (i4 >= S_LEN * INNER / 4) return;
  int s = i4 / (INNER / 4);
  int cg = i4 - s * (INNER / 4);                 // 4-channel group
  float4 acc = ((const float4*)cb)[cg];
  #pragma unroll
  for (int k = 0; k < NCONV; ++k) {
    int t = s - (NCONV - 1) + k;
    if (t >= 0) {
      float4 xv = *(const float4*)(xz + (size_t)t * (2 * INNER) + cg * 4);
      float4 wv = ((const float4*)(cw + k * INNER))[cg];
      acc.x += xv.x * wv.x; acc.y += xv.y * wv.y;
      acc.z += xv.z * wv.z; acc.w += xv.w * wv.w;
    }
  }
  float4 v;
  v.x = acc.x / (1.f + fexp(-acc.x));
  v.y = acc.y / (1.f + fexp(-acc.y));
  v.z = acc.z / (1.f + fexp(-acc.z));
  v.w = acc.w / (1.f + fexp(-acc.w));
  ((float4*)xc)[i4] = v;
  short4 o;
  o.x = f2bf(v.x); o.y = f2bf(v.y); o.z = f2bf(v.z); o.w = f2bf(v.w);
  ((short4*)xcb)[i4] = o;
}

// ---------------- chunk-parallel SSM scan (3 passes) ------------------------
// one thread per d-channel; 16 l-states in registers; B/C staged in LDS.
// (separate dispatches — grid-wide cooperative sync measured 60-80 us/sync
//  on 8-XCD MI355X (R15), far worse than ~3 us dispatch boundaries)

__global__ __launch_bounds__(256) void scan_pass1(
    const float* __restrict__ delta,
    const float* __restrict__ xp,
    const float* __restrict__ xc,
    const float* __restrict__ A_log,
    float* __restrict__ Aprod,
    float* __restrict__ Hend) {
  __shared__ float Bc[CHUNK][LSTATE];   // 2 KB
  const int tid = threadIdx.x;
  const int d = blockIdx.y * 256 + tid;
  const int c = blockIdx.x;
  const int s0 = c * CHUNK;
  for (int u = tid; u < CHUNK * LSTATE; u += 256) {
    int r = u >> 4, l = u & 15;
    Bc[r][l] = xp[(size_t)(s0 + r) * XPW + DRANK + l];
  }
  float a[LSTATE];
  {
    const float4* Ar = (const float4*)(A_log + (size_t)d * LSTATE);
    #pragma unroll
    for (int q = 0; q < 4; ++q) {
      float4 v = Ar[q];
      a[q * 4 + 0] = -fexp(v.x);
      a[q * 4 + 1] = -fexp(v.y);
      a[q * 4 + 2] = -fexp(v.z);
      a[q * 4 + 3] = -fexp(v.w);
    }
  }
  float h[LSTATE] = {}, ap[LSTATE];
  #pragma unroll
  for (int l = 0; l < LSTATE; ++l) ap[l] = 1.f;
  __syncthreads();
  const float* pd = delta + (size_t)s0 * INNER + d;
  const float* px = xc    + (size_t)s0 * INNER + d;
  for (int i = 0; i < CHUNK; ++i) {
    float dv = *pd, xcv = *px;
    pd += INNER; px += INNER;
    float sc = dv * xcv;
    #pragma unroll
    for (int l = 0; l < LSTATE; ++l) {
      float dA = fexp(dv * a[l]);
      h[l] = fmaf(dA, h[l], sc * Bc[i][l]);
      ap[l] *= dA;
    }
  }
  float4* Ap = (float4*)(Aprod + ((size_t)c * INNER + d) * LSTATE);
  float4* Hp = (float4*)(Hend  + ((size_t)c * INNER + d) * LSTATE);
  #pragma unroll
  for (int q = 0; q < 4; ++q) {
    Ap[q] = make_float4(ap[q * 4], ap[q * 4 + 1], ap[q * 4 + 2], ap[q * 4 + 3]);
    Hp[q] = make_float4(h[q * 4], h[q * 4 + 1], h[q * 4 + 2], h[q * 4 + 3]);
  }
}

// pass2: compose chunk carries. Batched loads (16 independent coalesced loads
// per wait) to collapse 64 serial latencies into 4.
__global__ __launch_bounds__(256) void scan_pass2(
    const float* __restrict__ Aprod, const float* __restrict__ Hend,
    float* __restrict__ Hin) {
  const int idx = blockIdx.x * 256 + threadIdx.x;
  const size_t stride = (size_t)INNER * LSTATE;
  float h = 0.f;
  for (int cb = 0; cb < NCHUNK; cb += 16) {
    float ap[16], he[16];
    #pragma unroll
    for (int j = 0; j < 16; ++j) {
      size_t o = (size_t)(cb + j) * stride + idx;
      ap[j] = Aprod[o];
      he[j] = Hend[o];
    }
    #pragma unroll
    for (int j = 0; j < 16; ++j) {
      size_t o = (size_t)(cb + j) * stride + idx;
      Hin[o] = h;
      h = ap[j] * h + he[j];
    }
  }
}

__global__ __launch_bounds__(256) void scan_pass3(
    const float* __restrict__ delta,
    const float* __restrict__ xp,
    const float* __restrict__ xc,
    const float* __restrict__ xz,
    const float* __restrict__ A_log,
    const float* __restrict__ Dvec,
    const float* __restrict__ Hin,
    short* __restrict__ ybf) {        // [S, INNER] bf16 (feeds gemm_bf16)
  __shared__ float Bc[CHUNK][LSTATE];
  __shared__ float Cc[CHUNK][LSTATE];
  const int tid = threadIdx.x;
  const int d = blockIdx.y * 256 + tid;
  const int c = blockIdx.x;
  const int s0 = c * CHUNK;
  for (int u = tid; u < CHUNK * LSTATE; u += 256) {
    int r = u >> 4, l = u & 15;
    size_t base = (size_t)(s0 + r) * XPW + DRANK;
    Bc[r][l] = xp[base + l];
    Cc[r][l] = xp[base + LSTATE + l];
  }
  float a[LSTATE], h[LSTATE];
  {
    const float4* Ar = (const float4*)(A_log + (size_t)d * LSTATE);
    #pragma unroll
    for (int q = 0; q < 4; ++q) {
      float4 v = Ar[q];
      a[q * 4 + 0] = -fexp(v.x);
      a[q * 4 + 1] = -fexp(v.y);
      a[q * 4 + 2] = -fexp(v.z);
      a[q * 4 + 3] = -fexp(v.w);
    }
    const float4* Hi = (const float4*)(Hin + ((size_t)c * INNER + d) * LSTATE);
    #pragma unroll
    for (int q = 0; q < 4; ++q) {
      float4 v = Hi[q];
      h[q * 4 + 0] = v.x; h[q * 4 + 1] = v.y;
      h[q * 4 + 2] = v.z; h[q * 4 + 3] = v.w;
    }
  }
  const float Dd = Dvec[d];
  __syncthreads();
  const float* pd = delta + (size_t)s0 * INNER + d;
  const float* px = xc    + (size_t)s0 * INNER + d;
  const float* pz = xz + (size_t)s0 * (2 * INNER) + INNER + d;
  short* py = ybf + (size_t)s0 * INNER + d;
  for (int i = 0; i < CHUNK; ++i) {
    float dv = *pd, xcv = *px, zv = *pz;
    pd += INNER; px += INNER; pz += 2 * INNER;
    float sc = dv * xcv;
    float contrib = 0.f;
    #pragma unroll
    for (int l = 0; l < LSTATE; ++l) {
      float dA = fexp(dv * a[l]);
      h[l] = fmaf(dA, h[l], sc * Bc[i][l]);
      contrib = fmaf(h[l], Cc[i][l], contrib);
    }
    float silu_z = zv / (1.f + fexp(-zv));
    *py = f2bf(fmaf(xcv, Dd, contrib) * silu_z);
    py += INNER;
  }
}

extern "C" void kernel_launch(void* const* d_in, const int* in_sizes, int n_in,
                              void* d_out, int out_size, void* d_ws, size_t ws_size,
                              hipStream_t stream) {
  const float* x      = (const float*)d_in[0];   // [S, HID]
  const float* W_in   = (const float*)d_in[1];   // [HID, 2*INNER]
  const float* conv_w = (const float*)d_in[2];   // [4,1,INNER]
  const float* conv_b = (const float*)d_in[3];   // [INNER]
  const float* W_x    = (const float*)d_in[4];   // [INNER, 96]
  const float* W_delta= (const float*)d_in[5];   // [DRANK, INNER]
  const float* b_delta= (const float*)d_in[6];   // [INNER]
  const float* A_log  = (const float*)d_in[7];   // [INNER, L]
  const float* Dvec   = (const float*)d_in[8];   // [INNER]
  const float* W_out  = (const float*)d_in[9];   // [INNER, HID]
  float* out = (float*)d_out;

  float* ws    = (float*)d_ws;
  float* xz    = ws;                               // S * 2*INNER
  float* xc    = xz + (size_t)S_LEN * 2 * INNER;   // S * INNER
  float* xp    = xc + (size_t)S_LEN * INNER;       // S * XPW
  float* delta = xp + (size_t)S_LEN * XPW;         // S * INNER
  float* Aprod = delta + (size_t)S_LEN * INNER;    // NCHUNK * INNER * L
  float* Hend  = Aprod + (size_t)NCHUNK * INNER * LSTATE;
  float* Hin   = Hend  + (size_t)NCHUNK * INNER * LSTATE;
  short* xb    = (short*)(Hin + (size_t)NCHUNK * INNER * LSTATE); // S*HID bf16
  short* WinT  = xb + (size_t)S_LEN * HID;          // [2*INNER, HID] bf16
  short* WoutT = WinT + (size_t)(2 * INNER) * HID;  // [HID, INNER] bf16
  short* ybf   = WoutT + (size_t)HID * INNER;       // [S, INNER] bf16
  short* xcb   = ybf + (size_t)S_LEN * INNER;       // [S, INNER] bf16
  short* WxT   = xcb + (size_t)S_LEN * INNER;       // [XPAD, INNER] bf16
  short* WdT   = WxT + (size_t)XPAD * INNER;        // [INNER, DRANK] bf16
  short* xpb64 = WdT + (size_t)INNER * DRANK;       // [S, DRANK] bf16
  // xp K-split partials [16][S][XPAD] = 16.8 MB alias Aprod..Hin (25.2 MB,
  // dead until the scan). out partials [2][S][HID] = 16.8 MB alias xc..delta
  // (dead after the scan).
  float* xpPart  = Aprod;
  float* outPart = xc;

  // 0. fused prep: cast x, transpose+cast W_in/W_out/W_x/W_delta
  prep_kernel<<<NB_PREP, 256, 0, stream>>>(
      x, xb, W_in, WinT, W_out, WoutT, W_x, WxT, W_delta, WdT);

  // 1. xz = x @ W_in   (M=2048, N=4096, K=1024)  [bf16 MFMA, 8-wave]
  gemm_bf16<0><<<dim3(4096 / 128, 2048 / 128, 1), 512, 0, stream>>>(
      xb, HID, WinT, HID, xz, 2 * INNER, HID, 0, nullptr);

  // 2. xc = silu(causal_depthwise_conv(xi) + conv_b)  (+ bf16 copy)
  conv_silu_kernel<<<(S_LEN * INNER / 4 + 255) / 256, 256, 0, stream>>>(
      xz, conv_w, conv_b, xc, xcb);

  // 3. xp = xc @ W_x   (M=2048, N=96, K=2048)  [bf16 MFMA, 16-way K-split]
  gemm_bf16<0><<<dim3(1, 2048 / 128, XPSPLIT), 512, 0, stream>>>(
      xcb, INNER, WxT, INNER, xpPart, XPAD, INNER / XPSPLIT,
      (size_t)S_LEN * XPAD, nullptr);
  reduce_xp_kernel<<<(S_LEN * (XPW / 4) + 255) / 256, 256, 0, stream>>>(
      xpPart, xp, xpb64);

  // 4. delta = softplus(xp[:, :64] @ W_delta + b_delta)  [bf16 MFMA + epi]
  gemm_bf16<1><<<dim3(2048 / 128, 2048 / 128, 1), 512, 0, stream>>>(
      xpb64, DRANK, WdT, DRANK, delta, INNER, DRANK, 0, b_delta);

  // 5. chunk-parallel SSM scan -> ybf (fused +xc*D, *silu(z), bf16 cast)
  scan_pass1<<<dim3(NCHUNK, INNER / 256), 256, 0, stream>>>(
      delta, xp, xc, A_log, Aprod, Hend);
  scan_pass2<<<(INNER * LSTATE) / 256, 256, 0, stream>>>(Aprod, Hend, Hin);
  scan_pass3<<<dim3(NCHUNK, INNER / 256), 256, 0, stream>>>(
      delta, xp, xc, xz, A_log, Dvec, Hin, ybf);

  // 6. out = y @ W_out  (M=2048, N=1024, K=2048)  [bf16 MFMA, 2-way K-split]
  gemm_bf16<0><<<dim3(1024 / 128, 2048 / 128, OSPLIT), 512, 0, stream>>>(
      ybf, INNER, WoutT, INNER, outPart, HID, INNER / OSPLIT,
      (size_t)S_LEN * HID, nullptr);
  reduce_out_kernel<<<(S_LEN * (HID / 4) + 255) / 256, 256, 0, stream>>>(
      outPart, out);
}

// Round 17
// 156.610 us; speedup vs baseline: 1.9545x; 1.0548x over previous
//
#include <hip/hip_runtime.h>
#include <hip/hip_bf16.h>
#include <math.h>

#define S_LEN 2048
#define HID   1024
#define INNER 2048
#define NCONV 4
#define LSTATE 16
#define DRANK 64
#define XPW   96   // DRANK + 2*LSTATE
#define CHUNK 32
#define NCHUNK (S_LEN / CHUNK)   // 64
#define XPAD  128  // padded N for the xp GEMM tile
#define XPSPLIT 16 // K-split for the xp GEMM
#define OSPLIT  2  // K-split for the out GEMM

typedef __attribute__((ext_vector_type(8))) short bf16x8;
typedef __attribute__((ext_vector_type(4))) float f32x4;

__device__ __forceinline__ short f2bf(float f) {
  union { __hip_bfloat16 h; short s; } u;
  u.h = __float2bfloat16(f);
  return u.s;
}
__device__ __forceinline__ float b2f(short s) {
  union { unsigned int u; float f; } v;
  v.u = ((unsigned int)(unsigned short)s) << 16;
  return v.f;
}

// fast exp: v_exp_f32-based (~1-2 ulp) — bf16 noise floor dominates anyway
__device__ __forceinline__ float fexp(float x) { return __expf(x); }

// async global->LDS, 16B per lane; lds dest = wave-uniform base + lane*16
#define GLDS(gp, lp) __builtin_amdgcn_global_load_lds(                         \
    (const __attribute__((address_space(1))) unsigned int*)(gp),               \
    (__attribute__((address_space(3))) unsigned int*)(lp), 16, 0, 0)

// ---------------- fused prep: cast x + transpose-cast 4 weights -------------
#define NB_CAST (S_LEN * HID / 4 / 256)            // 2048
#define NB_WIN  ((2 * INNER / 32) * (HID / 32))    // 4096
#define NB_WOUT ((HID / 32) * (INNER / 32))        // 2048
#define NB_WX   ((XPAD / 32) * (INNER / 32))       // 256
#define NB_WD   ((INNER / 32) * (DRANK / 32))      // 128
#define NB_PREP (NB_CAST + NB_WIN + NB_WOUT + NB_WX + NB_WD)
__global__ __launch_bounds__(256) void prep_kernel(
    const float* __restrict__ x, short* __restrict__ xb,
    const float* __restrict__ W_in, short* __restrict__ WinT,
    const float* __restrict__ W_out, short* __restrict__ WoutT,
    const float* __restrict__ W_x, short* __restrict__ WxT,
    const float* __restrict__ W_delta, short* __restrict__ WdT) {
  const int b = blockIdx.x;
  if (b < NB_CAST) {                       // cast x -> xb (bf16), float4/thread
    int i = b * 256 + threadIdx.x;
    const float4 v = ((const float4*)x)[i];
    short4 o;
    o.x = f2bf(v.x); o.y = f2bf(v.y); o.z = f2bf(v.z); o.w = f2bf(v.w);
    ((short4*)xb)[i] = o;
    return;
  }
  // transpose+cast in[R][C] -> out[Cpad][R], pad cols >= C zeroed
  __shared__ float tile[32][33];
  const float* in; short* outp; int R, C, bx, by;
  if (b < NB_CAST + NB_WIN) {
    int bb = b - NB_CAST;
    in = W_in; outp = WinT; R = HID; C = 2 * INNER;
    bx = bb % (2 * INNER / 32); by = bb / (2 * INNER / 32);
  } else if (b < NB_CAST + NB_WIN + NB_WOUT) {
    int bb = b - NB_CAST - NB_WIN;
    in = W_out; outp = WoutT; R = INNER; C = HID;
    bx = bb % (HID / 32); by = bb / (HID / 32);
  } else if (b < NB_CAST + NB_WIN + NB_WOUT + NB_WX) {
    int bb = b - NB_CAST - NB_WIN - NB_WOUT;
    in = W_x; outp = WxT; R = INNER; C = XPW;   // grid covers Cpad=XPAD
    bx = bb % (XPAD / 32); by = bb / (XPAD / 32);
  } else {
    int bb = b - NB_CAST - NB_WIN - NB_WOUT - NB_WX;
    in = W_delta; outp = WdT; R = DRANK; C = INNER;   // -> WdT[2048][64]
    bx = bb % (INNER / 32); by = bb / (INNER / 32);
  }
  const int bc = bx * 32, br = by * 32;
  const int tx = threadIdx.x & 31, ty = threadIdx.x >> 5;   // 32 x 8
  #pragma unroll
  for (int i = 0; i < 32; i += 8)
    tile[ty + i][tx] = (bc + tx < C)
        ? in[(size_t)(br + ty + i) * C + bc + tx] : 0.f;
  __syncthreads();
  #pragma unroll
  for (int i = 0; i < 32; i += 8)
    outp[(size_t)(bc + ty + i) * R + br + tx] = f2bf(tile[tx][ty + i]);
}

// --------------- bf16 MFMA GEMM: C[M,N] = A[M,K] @ Bt[N,K]^T ---------------
// 128x128 tile, BK=32, 8 waves (2M x 4N). 4-buffer pipeline, depth-3 counted
// vmcnt (T4). LDS 16B-slot XOR swizzle (involution, rule #21) -> 0 conflicts.
// EPI: 0 = f32 store (K-split via blockIdx.z), 2 = bf16 store,
//      3 = softplus(acc + bias[col]) -> bf16 store.
#define BK   32
#define NBUF 4
template<int EPI>
__global__ __launch_bounds__(512) void gemm_bf16(
    const short* __restrict__ A,  int lda,    // [M,K] bf16 row-major
    const short* __restrict__ Bt, int ldb,    // [N,K] bf16 row-major
    void* __restrict__ Cv, int ldc,
    int kPerSplit, size_t cSliceStride,
    const float* __restrict__ bias) {
  __shared__ short As[NBUF][128 * BK];
  __shared__ short Bs[NBUF][128 * BK];
  const int tid  = threadIdx.x;
  const int lane = tid & 63;
  const int wave = tid >> 6;                  // 0..7
  const int bm = blockIdx.y * 128;
  const int bn = blockIdx.x * 128;
  const int wm = (wave & 1) * 64;             // 2 M-waves
  const int wn = (wave >> 1) * 32;            // 4 N-waves
  const int fr = lane & 15;
  const int fq = lane >> 4;
  const int kbeg = blockIdx.z * kPerSplit;
  const int nIter = kPerSplit / BK;
  float* Cf = (float*)Cv + (size_t)blockIdx.z * cSliceStride;
  short* Cs = (short*)Cv;

  // staging geometry: waves 0-3 stage A rows [sw*32,+32), waves 4-7 stage B
  const int sw  = wave & 3;
  const int rs0 = sw * 32 + (lane >> 2);
  const int rs1 = rs0 + 16;
  const int sg0 = (lane & 3) ^ ((rs0 >> 1) & 3);  // source 16B chunk (swz)
  const int sg1 = (lane & 3) ^ ((rs1 >> 1) & 3);
  const bool isB = wave >= 4;
  const short* gbase = isB ? Bt : A;
  const int    gld   = isB ? ldb : lda;
  const int    gro   = isB ? bn  : bm;
  const short* g0 = gbase + (size_t)(gro + rs0) * gld + kbeg + sg0 * 8;
  const short* g1 = gbase + (size_t)(gro + rs1) * gld + kbeg + sg1 * 8;
  const int lo0 = (sw * 32) * BK;             // shorts
  const int lo1 = (sw * 32 + 16) * BK;

  f32x4 acc[4][2] = {};

#define STAGE(tile, buf) do {                                                  \
    short* dst_ = isB ? &Bs[buf][0] : &As[buf][0];                             \
    const int ko_ = (tile) * BK;                                               \
    GLDS(g0 + ko_, dst_ + lo0);                                                \
    GLDS(g1 + ko_, dst_ + lo1);                                                \
  } while (0)

  STAGE(0, 0);
  if (nIter > 1) STAGE(1, 1);
  if (nIter > 2) STAGE(2, 2);

  const int sl = (fq ^ ((fr >> 1) & 3)) * 8;  // read-side swizzled slot
  for (int t = 0; t < nIter; ++t) {
    const int rem = nIter - 1 - t;
    if (rem >= 2)      asm volatile("s_waitcnt vmcnt(4)" ::: "memory");
    else if (rem == 1) asm volatile("s_waitcnt vmcnt(2)" ::: "memory");
    else               asm volatile("s_waitcnt vmcnt(0)" ::: "memory");
    asm volatile("s_barrier" ::: "memory");
    if (t + 3 < nIter) STAGE(t + 3, (t + 3) & 3);
    const int r = t & 3;
    bf16x8 af[4], bfv[2];
    #pragma unroll
    for (int mi = 0; mi < 4; ++mi)
      af[mi] = *(const bf16x8*)(&As[r][(wm + mi * 16 + fr) * BK + sl]);
    #pragma unroll
    for (int ni = 0; ni < 2; ++ni)
      bfv[ni] = *(const bf16x8*)(&Bs[r][(wn + ni * 16 + fr) * BK + sl]);
    #pragma unroll
    for (int mi = 0; mi < 4; ++mi)
      #pragma unroll
      for (int ni = 0; ni < 2; ++ni)
        acc[mi][ni] = __builtin_amdgcn_mfma_f32_16x16x32_bf16(
            af[mi], bfv[ni], acc[mi][ni], 0, 0, 0);
  }
#undef STAGE
  // C/D layout (m89): col = lane&15, row = (lane>>4)*4 + reg
  #pragma unroll
  for (int mi = 0; mi < 4; ++mi) {
    #pragma unroll
    for (int ni = 0; ni < 2; ++ni) {
      const int col = bn + wn + ni * 16 + fr;
      #pragma unroll
      for (int r = 0; r < 4; ++r) {
        const int row = bm + wm + mi * 16 + fq * 4 + r;
        float v = acc[mi][ni][r];
        if (EPI == 0) {
          Cf[(size_t)row * ldc + col] = v;
        } else if (EPI == 2) {
          Cs[(size_t)row * ldc + col] = f2bf(v);
        } else {
          v += bias[col];
          v = fmaxf(v, 0.f) + log1pf(expf(-fabsf(v)));   // softplus (precise)
          Cs[(size_t)row * ldc + col] = f2bf(v);
        }
      }
    }
  }
}

// ---- reduce XPSPLIT partials [Z][S][XPAD] -> xp [S][XPW] + xpb64 bf16 ------
__global__ __launch_bounds__(256) void reduce_xp_kernel(
    const float* __restrict__ part, float* __restrict__ xp,
    short* __restrict__ xpb64) {
  int i4 = blockIdx.x * 256 + threadIdx.x;
  if (i4 >= S_LEN * (XPW / 4)) return;
  int m = i4 / (XPW / 4);
  int n4 = i4 - m * (XPW / 4);
  const float4* p = (const float4*)part;
  const size_t rowv = (size_t)m * (XPAD / 4) + n4;
  const size_t slice = (size_t)S_LEN * (XPAD / 4);
  float4 o = p[rowv];
  #pragma unroll
  for (int s = 1; s < XPSPLIT; ++s) {   // fixed order: deterministic
    float4 v = p[rowv + s * slice];
    o.x += v.x; o.y += v.y; o.z += v.z; o.w += v.w;
  }
  ((float4*)xp)[i4] = o;
  if (n4 < DRANK / 4) {                 // bf16 copy of delta-GEMM A-operand
    short4 s4;
    s4.x = f2bf(o.x); s4.y = f2bf(o.y); s4.z = f2bf(o.z); s4.w = f2bf(o.w);
    ((short4*)xpb64)[m * (DRANK / 4) + n4] = s4;
  }
}

// ------------- reduce OSPLIT partials [Z][S][HID] -> out --------------------
__global__ __launch_bounds__(256) void reduce_out_kernel(
    const float* __restrict__ part, float* __restrict__ out) {
  int i4 = blockIdx.x * 256 + threadIdx.x;
  if (i4 >= S_LEN * (HID / 4)) return;
  const float4* p = (const float4*)part;
  const size_t slice = (size_t)S_LEN * (HID / 4);
  float4 o = p[i4];
  #pragma unroll
  for (int s = 1; s < OSPLIT; ++s) {
    float4 v = p[i4 + s * slice];
    o.x += v.x; o.y += v.y; o.z += v.z; o.w += v.w;
  }
  ((float4*)out)[i4] = o;
}

// --- depthwise causal conv (width 4) + bias + SiLU, bf16 in/out, 4ch/thread -
__global__ __launch_bounds__(256) void conv_silu_kernel(
    const short* __restrict__ xzb,   // [S, 2*INNER] bf16; xi = cols [0,INNER)
    const float* __restrict__ cw,
    const float* __restrict__ cb,
    short* __restrict__ xcb) {       // [S, INNER] bf16
  int i4 = blockIdx.x * 256 + threadIdx.x;       // over S*INNER/4
  if (i4 >= S_LEN * INNER / 4) return;
  int s = i4 / (INNER / 4);
  int cg = i4 - s * (INNER / 4);                 // 4-channel group
  float4 acc = ((const float4*)cb)[cg];
  #pragma unroll
  for (int k = 0; k < NCONV; ++k) {
    int t = s - (NCONV - 1) + k;
    if (t >= 0) {
      short4 xv = *(const short4*)(xzb + (size_t)t * (2 * INNER) + cg * 4);
      float4 wv = ((const float4*)(cw + k * INNER))[cg];
      acc.x += b2f(xv.x) * wv.x; acc.y += b2f(xv.y) * wv.y;
      acc.z += b2f(xv.z) * wv.z; acc.w += b2f(xv.w) * wv.w;
    }
  }
  short4 o;
  o.x = f2bf(acc.x / (1.f + fexp(-acc.x)));
  o.y = f2bf(acc.y / (1.f + fexp(-acc.y)));
  o.z = f2bf(acc.z / (1.f + fexp(-acc.z)));
  o.w = f2bf(acc.w / (1.f + fexp(-acc.w)));
  ((short4*)xcb)[i4] = o;
}

// ---------------- chunk-parallel SSM scan (3 passes) ------------------------
// one thread per d-channel; 16 l-states in registers; B/C staged in LDS.
// delta/xc/z inputs are bf16 (half the stream traffic of fp32).
// (separate dispatches — grid-wide cooperative sync measured 60-80 us/sync
//  on 8-XCD MI355X (R15), far worse than ~3 us dispatch boundaries)

__global__ __launch_bounds__(256) void scan_pass1(
    const short* __restrict__ deltab,  // [S, INNER] bf16
    const float* __restrict__ xp,
    const short* __restrict__ xcb,     // [S, INNER] bf16
    const float* __restrict__ A_log,
    float* __restrict__ Aprod,
    float* __restrict__ Hend) {
  __shared__ float Bc[CHUNK][LSTATE];   // 2 KB
  const int tid = threadIdx.x;
  const int d = blockIdx.y * 256 + tid;
  const int c = blockIdx.x;
  const int s0 = c * CHUNK;
  for (int u = tid; u < CHUNK * LSTATE; u += 256) {
    int r = u >> 4, l = u & 15;
    Bc[r][l] = xp[(size_t)(s0 + r) * XPW + DRANK + l];
  }
  float a[LSTATE];
  {
    const float4* Ar = (const float4*)(A_log + (size_t)d * LSTATE);
    #pragma unroll
    for (int q = 0; q < 4; ++q) {
      float4 v = Ar[q];
      a[q * 4 + 0] = -fexp(v.x);
      a[q * 4 + 1] = -fexp(v.y);
      a[q * 4 + 2] = -fexp(v.z);
      a[q * 4 + 3] = -fexp(v.w);
    }
  }
  float h[LSTATE] = {}, ap[LSTATE];
  #pragma unroll
  for (int l = 0; l < LSTATE; ++l) ap[l] = 1.f;
  __syncthreads();
  const short* pd = deltab + (size_t)s0 * INNER + d;
  const short* px = xcb    + (size_t)s0 * INNER + d;
  for (int i = 0; i < CHUNK; ++i) {
    float dv = b2f(*pd), xcv = b2f(*px);
    pd += INNER; px += INNER;
    float sc = dv * xcv;
    #pragma unroll
    for (int l = 0; l < LSTATE; ++l) {
      float dA = fexp(dv * a[l]);
      h[l] = fmaf(dA, h[l], sc * Bc[i][l]);
      ap[l] *= dA;
    }
  }
  float4* Ap = (float4*)(Aprod + ((size_t)c * INNER + d) * LSTATE);
  float4* Hp = (float4*)(Hend  + ((size_t)c * INNER + d) * LSTATE);
  #pragma unroll
  for (int q = 0; q < 4; ++q) {
    Ap[q] = make_float4(ap[q * 4], ap[q * 4 + 1], ap[q * 4 + 2], ap[q * 4 + 3]);
    Hp[q] = make_float4(h[q * 4], h[q * 4 + 1], h[q * 4 + 2], h[q * 4 + 3]);
  }
}

// pass2: compose chunk carries. Batched loads (16 independent coalesced loads
// per wait) to collapse 64 serial latencies into 4.
__global__ __launch_bounds__(256) void scan_pass2(
    const float* __restrict__ Aprod, const float* __restrict__ Hend,
    float* __restrict__ Hin) {
  const int idx = blockIdx.x * 256 + threadIdx.x;
  const size_t stride = (size_t)INNER * LSTATE;
  float h = 0.f;
  for (int cb = 0; cb < NCHUNK; cb += 16) {
    float ap[16], he[16];
    #pragma unroll
    for (int j = 0; j < 16; ++j) {
      size_t o = (size_t)(cb + j) * stride + idx;
      ap[j] = Aprod[o];
      he[j] = Hend[o];
    }
    #pragma unroll
    for (int j = 0; j < 16; ++j) {
      size_t o = (size_t)(cb + j) * stride + idx;
      Hin[o] = h;
      h = ap[j] * h + he[j];
    }
  }
}

__global__ __launch_bounds__(256) void scan_pass3(
    const short* __restrict__ deltab,  // [S, INNER] bf16
    const float* __restrict__ xp,
    const short* __restrict__ xcb,     // [S, INNER] bf16
    const short* __restrict__ xzb,     // [S, 2*INNER] bf16; z = cols [INNER,)
    const float* __restrict__ A_log,
    const float* __restrict__ Dvec,
    const float* __restrict__ Hin,
    short* __restrict__ ybf) {         // [S, INNER] bf16 (feeds gemm_bf16)
  __shared__ float Bc[CHUNK][LSTATE];
  __shared__ float Cc[CHUNK][LSTATE];
  const int tid = threadIdx.x;
  const int d = blockIdx.y * 256 + tid;
  const int c = blockIdx.x;
  const int s0 = c * CHUNK;
  for (int u = tid; u < CHUNK * LSTATE; u += 256) {
    int r = u >> 4, l = u & 15;
    size_t base = (size_t)(s0 + r) * XPW + DRANK;
    Bc[r][l] = xp[base + l];
    Cc[r][l] = xp[base + LSTATE + l];
  }
  float a[LSTATE], h[LSTATE];
  {
    const float4* Ar = (const float4*)(A_log + (size_t)d * LSTATE);
    #pragma unroll
    for (int q = 0; q < 4; ++q) {
      float4 v = Ar[q];
      a[q * 4 + 0] = -fexp(v.x);
      a[q * 4 + 1] = -fexp(v.y);
      a[q * 4 + 2] = -fexp(v.z);
      a[q * 4 + 3] = -fexp(v.w);
    }
    const float4* Hi = (const float4*)(Hin + ((size_t)c * INNER + d) * LSTATE);
    #pragma unroll
    for (int q = 0; q < 4; ++q) {
      float4 v = Hi[q];
      h[q * 4 + 0] = v.x; h[q * 4 + 1] = v.y;
      h[q * 4 + 2] = v.z; h[q * 4 + 3] = v.w;
    }
  }
  const float Dd = Dvec[d];
  __syncthreads();
  const short* pd = deltab + (size_t)s0 * INNER + d;
  const short* px = xcb    + (size_t)s0 * INNER + d;
  const short* pz = xzb + (size_t)s0 * (2 * INNER) + INNER + d;
  short* py = ybf + (size_t)s0 * INNER + d;
  for (int i = 0; i < CHUNK; ++i) {
    float dv = b2f(*pd), xcv = b2f(*px), zv = b2f(*pz);
    pd += INNER; px += INNER; pz += 2 * INNER;
    float sc = dv * xcv;
    float contrib = 0.f;
    #pragma unroll
    for (int l = 0; l < LSTATE; ++l) {
      float dA = fexp(dv * a[l]);
      h[l] = fmaf(dA, h[l], sc * Bc[i][l]);
      contrib = fmaf(h[l], Cc[i][l], contrib);
    }
    float silu_z = zv / (1.f + fexp(-zv));
    *py = f2bf(fmaf(xcv, Dd, contrib) * silu_z);
    py += INNER;
  }
}

extern "C" void kernel_launch(void* const* d_in, const int* in_sizes, int n_in,
                              void* d_out, int out_size, void* d_ws, size_t ws_size,
                              hipStream_t stream) {
  const float* x      = (const float*)d_in[0];   // [S, HID]
  const float* W_in   = (const float*)d_in[1];   // [HID, 2*INNER]
  const float* conv_w = (const float*)d_in[2];   // [4,1,INNER]
  const float* conv_b = (const float*)d_in[3];   // [INNER]
  const float* W_x    = (const float*)d_in[4];   // [INNER, 96]
  const float* W_delta= (const float*)d_in[5];   // [DRANK, INNER]
  const float* b_delta= (const float*)d_in[6];   // [INNER]
  const float* A_log  = (const float*)d_in[7];   // [INNER, L]
  const float* Dvec   = (const float*)d_in[8];   // [INNER]
  const float* W_out  = (const float*)d_in[9];   // [INNER, HID]
  float* out = (float*)d_out;

  float* ws    = (float*)d_ws;
  float* xp    = ws;                               // S * XPW            fp32
  float* Aprod = xp + (size_t)S_LEN * XPW;         // NCHUNK*INNER*L     fp32
  float* Hend  = Aprod + (size_t)NCHUNK * INNER * LSTATE;
  float* Hin   = Hend  + (size_t)NCHUNK * INNER * LSTATE;
  short* xzb   = (short*)(Hin + (size_t)NCHUNK * INNER * LSTATE); // S*2INNER
  short* xb    = xzb + (size_t)S_LEN * 2 * INNER;   // [S, HID] bf16
  short* WinT  = xb + (size_t)S_LEN * HID;          // [2*INNER, HID] bf16
  short* WoutT = WinT + (size_t)(2 * INNER) * HID;  // [HID, INNER] bf16
  short* ybf   = WoutT + (size_t)HID * INNER;       // [S, INNER] bf16
  short* xcb   = ybf + (size_t)S_LEN * INNER;       // [S, INNER] bf16
  short* WxT   = xcb + (size_t)S_LEN * INNER;       // [XPAD, INNER] bf16
  short* WdT   = WxT + (size_t)XPAD * INNER;        // [INNER, DRANK] bf16
  short* xpb64 = WdT + (size_t)INNER * DRANK;       // [S, DRANK] bf16
  short* deltab= xpb64 + (size_t)S_LEN * DRANK;     // [S, INNER] bf16
  // K-split partials alias the Aprod..Hin region (25.2 MB):
  //   xp partials [16][S][XPAD] = 16.8 MB (dead until scan_pass1)
  //   out partials [2][S][HID]  = 16.8 MB (scan fully done by GEMM6 time)
  float* xpPart  = Aprod;
  float* outPart = Aprod;

  // 0. fused prep: cast x, transpose+cast W_in/W_out/W_x/W_delta
  prep_kernel<<<NB_PREP, 256, 0, stream>>>(
      x, xb, W_in, WinT, W_out, WoutT, W_x, WxT, W_delta, WdT);

  // 1. xz = x @ W_in   (M=2048, N=4096, K=1024)  [bf16 MFMA -> bf16 store]
  gemm_bf16<2><<<dim3(4096 / 128, 2048 / 128, 1), 512, 0, stream>>>(
      xb, HID, WinT, HID, xzb, 2 * INNER, HID, 0, nullptr);

  // 2. xc = silu(causal_depthwise_conv(xi) + conv_b)  -> bf16
  conv_silu_kernel<<<(S_LEN * INNER / 4 + 255) / 256, 256, 0, stream>>>(
      xzb, conv_w, conv_b, xcb);

  // 3. xp = xc @ W_x   (M=2048, N=96, K=2048)  [bf16 MFMA, 16-way K-split]
  gemm_bf16<0><<<dim3(1, 2048 / 128, XPSPLIT), 512, 0, stream>>>(
      xcb, INNER, WxT, INNER, xpPart, XPAD, INNER / XPSPLIT,
      (size_t)S_LEN * XPAD, nullptr);
  reduce_xp_kernel<<<(S_LEN * (XPW / 4) + 255) / 256, 256, 0, stream>>>(
      xpPart, xp, xpb64);

  // 4. delta = softplus(xp[:, :64] @ W_delta + b_delta)  [bf16 MFMA -> bf16]
  gemm_bf16<3><<<dim3(2048 / 128, 2048 / 128, 1), 512, 0, stream>>>(
      xpb64, DRANK, WdT, DRANK, deltab, INNER, DRANK, 0, b_delta);

  // 5. chunk-parallel SSM scan -> ybf (fused +xc*D, *silu(z), bf16 cast)
  scan_pass1<<<dim3(NCHUNK, INNER / 256), 256, 0, stream>>>(
      deltab, xp, xcb, A_log, Aprod, Hend);
  scan_pass2<<<(INNER * LSTATE) / 256, 256, 0, stream>>>(Aprod, Hend, Hin);
  scan_pass3<<<dim3(NCHUNK, INNER / 256), 256, 0, stream>>>(
      deltab, xp, xcb, xzb, A_log, Dvec, Hin, ybf);

  // 6. out = y @ W_out  (M=2048, N=1024, K=2048)  [bf16 MFMA, 2-way K-split]
  gemm_bf16<0><<<dim3(1024 / 128, 2048 / 128, OSPLIT), 512, 0, stream>>>(
      ybf, INNER, WoutT, INNER, outPart, HID, INNER / OSPLIT,
      (size_t)S_LEN * HID, nullptr);
  reduce_out_kernel<<<(S_LEN * (HID / 4) + 255) / 256, 256, 0, stream>>>(
      outPart, out);
}